// Round 1
// baseline (58.970 us; speedup 1.0000x reference)
//
#include <hip/hip_runtime.h>
#include <math.h>

#define BATCH   512
#define IN_DIM  256
#define OUT_DIM 256
#define NDEG    6   // degree+1

// ---------------------------------------------------------------------------
// Restructure: LSE_d(x*d + w_d) = log( sum_d e^{w_d} * t^d ),  t = e^x.
// out[b,o] = sum_i log(P_io(t_bi)) - log(Q_io(t_bi))
// P,Q are degree-5 polys with positive coefficients exp(w).
// Precompute exp(w) (packed 12 floats per (i,o)) and exp(x) in workspace.
// ---------------------------------------------------------------------------

__global__ void prep_pack(const float* __restrict__ wp,
                          const float* __restrict__ wq,
                          float* __restrict__ pk) {
    int j = blockIdx.x * blockDim.x + threadIdx.x;   // j = i*OUT_DIM + o
    if (j >= IN_DIM * OUT_DIM) return;
#pragma unroll
    for (int d = 0; d < NDEG; ++d) {
        pk[j * 12 + d]        = __expf(wp[j * NDEG + d]);
        pk[j * 12 + NDEG + d] = __expf(wq[j * NDEG + d]);
    }
}

__global__ void prep_texp(const float* __restrict__ x, float* __restrict__ texp) {
    int k = blockIdx.x * blockDim.x + threadIdx.x;
    if (k >= BATCH * IN_DIM) return;
    texp[k] = __expf(x[k]);
}

// Block = 256 threads = 16 b x 16 o. Grid = (OUT_DIM/16, BATCH/16).
__launch_bounds__(256, 4)
__global__ void tropical_main(const float* __restrict__ texp,
                              const float4* __restrict__ pk4,
                              float* __restrict__ out) {
    const int o_sub = threadIdx.x & 15;
    const int b_sub = threadIdx.x >> 4;
    const int o = blockIdx.x * 16 + o_sub;
    const int b = blockIdx.y * 16 + b_sub;

    const float* tx = texp + b * IN_DIM;
    float accP = 0.f, accQ = 0.f;

#pragma unroll 4
    for (int i = 0; i < IN_DIM; ++i) {
        const float t  = tx[i];
        const float t2 = t * t;
        const float t3 = t2 * t;
        const float t4 = t2 * t2;
        const float t5 = t3 * t2;
        const float4* c = pk4 + (size_t)(i * OUT_DIM + o) * 3;
        const float4 c0 = c[0];   // cp0 cp1 cp2 cp3
        const float4 c1 = c[1];   // cp4 cp5 cq0 cq1
        const float4 c2 = c[2];   // cq2 cq3 cq4 cq5
        const float P = fmaf(c1.y, t5, fmaf(c1.x, t4, fmaf(c0.w, t3,
                        fmaf(c0.z, t2, fmaf(c0.y, t, c0.x)))));
        const float Q = fmaf(c2.w, t5, fmaf(c2.z, t4, fmaf(c2.y, t3,
                        fmaf(c2.x, t2, fmaf(c1.w, t, c1.z)))));
        accP += __log2f(P);
        accQ += __log2f(Q);
    }
    out[b * OUT_DIM + o] = (accP - accQ) * 0.6931471805599453f;  // *ln2
}

// Fallback (workspace too small): direct stabilized LSE, still one thread/output.
__global__ void tropical_fallback(const float* __restrict__ x,
                                  const float* __restrict__ wp,
                                  const float* __restrict__ wq,
                                  float* __restrict__ out) {
    const int o = blockIdx.x * 16 + (threadIdx.x & 15);
    const int b = blockIdx.y * 16 + (threadIdx.x >> 4);
    float acc = 0.f;
    for (int i = 0; i < IN_DIM; ++i) {
        const float xv = x[b * IN_DIM + i];
        const float* p = wp + (size_t)(i * OUT_DIM + o) * NDEG;
        const float* q = wq + (size_t)(i * OUT_DIM + o) * NDEG;
        float lp[NDEG], lq[NDEG], mP = -1e30f, mQ = -1e30f;
#pragma unroll
        for (int d = 0; d < NDEG; ++d) {
            lp[d] = xv * d + p[d]; mP = fmaxf(mP, lp[d]);
            lq[d] = xv * d + q[d]; mQ = fmaxf(mQ, lq[d]);
        }
        float sP = 0.f, sQ = 0.f;
#pragma unroll
        for (int d = 0; d < NDEG; ++d) {
            sP += __expf(lp[d] - mP);
            sQ += __expf(lq[d] - mQ);
        }
        acc += (mP + __logf(sP)) - (mQ + __logf(sQ));
    }
    out[b * OUT_DIM + o] = acc;
}

extern "C" void kernel_launch(void* const* d_in, const int* in_sizes, int n_in,
                              void* d_out, int out_size, void* d_ws, size_t ws_size,
                              hipStream_t stream) {
    const float* x  = (const float*)d_in[0];
    // d_in[1] = slopes (arange(6)) — implicit in the polynomial powers.
    const float* wp = (const float*)d_in[2];
    const float* wq = (const float*)d_in[3];
    float* out = (float*)d_out;

    const size_t pk_bytes   = (size_t)IN_DIM * OUT_DIM * 12 * sizeof(float); // 3 MiB
    const size_t texp_bytes = (size_t)BATCH * IN_DIM * sizeof(float);        // 0.5 MiB

    if (ws_size >= pk_bytes + texp_bytes) {
        float* pk   = (float*)d_ws;
        float* texp = (float*)((char*)d_ws + pk_bytes);

        prep_pack<<<(IN_DIM * OUT_DIM + 255) / 256, 256, 0, stream>>>(wp, wq, pk);
        prep_texp<<<(BATCH * IN_DIM + 255) / 256, 256, 0, stream>>>(x, texp);

        dim3 grid(OUT_DIM / 16, BATCH / 16);
        tropical_main<<<grid, 256, 0, stream>>>(texp, (const float4*)pk, out);
    } else {
        dim3 grid(OUT_DIM / 16, BATCH / 16);
        tropical_fallback<<<grid, 256, 0, stream>>>(x, wp, wq, out);
    }
}

// Round 2
// 56.478 us; speedup vs baseline: 1.0441x; 1.0441x over previous
//
#include <hip/hip_runtime.h>
#include <math.h>

#define BATCH   512
#define IN_DIM  256
#define OUT_DIM 256
#define NDEG    6    // degree+1
#define ICHUNK  64
#define NCHUNK  4    // ICHUNK * NCHUNK == IN_DIM

// ---------------------------------------------------------------------------
// LSE_d(x*d + w_d) = log( sum_d e^{w_d} * t^d ),  t = e^x.
// out[b,o] = sum_i log2(P_io(t_bi)) - log2(Q_io(t_bi)), scaled by ln2 at the end.
// P,Q: degree-5 polys, positive coeffs exp(w) precomputed (12 floats/(i,o)).
// i-loop split 4-way across blockIdx.z for occupancy; partials reduced after.
// ---------------------------------------------------------------------------

__global__ void prep_pack(const float* __restrict__ wp,
                          const float* __restrict__ wq,
                          float4* __restrict__ pk4) {
    int j = blockIdx.x * blockDim.x + threadIdx.x;   // j = i*OUT_DIM + o
    if (j >= IN_DIM * OUT_DIM) return;
    const float2* wp2 = (const float2*)wp;
    const float2* wq2 = (const float2*)wq;
    float2 p0 = wp2[j * 3], p1 = wp2[j * 3 + 1], p2 = wp2[j * 3 + 2];
    float2 q0 = wq2[j * 3], q1 = wq2[j * 3 + 1], q2 = wq2[j * 3 + 2];
    pk4[j * 3 + 0] = make_float4(__expf(p0.x), __expf(p0.y), __expf(p1.x), __expf(p1.y));
    pk4[j * 3 + 1] = make_float4(__expf(p2.x), __expf(p2.y), __expf(q0.x), __expf(q0.y));
    pk4[j * 3 + 2] = make_float4(__expf(q1.x), __expf(q1.y), __expf(q2.x), __expf(q2.y));
}

// Block = 256 threads = 16 b x 16 o. Grid = (OUT/16, BATCH/16, NCHUNK).
__launch_bounds__(256, 8)
__global__ void tropical_main(const float* __restrict__ x,
                              const float4* __restrict__ pk4,
                              float* __restrict__ partial) {
    __shared__ float t_lds[16][ICHUNK + 1];   // +1 pad: rows hit distinct banks

    const int o_sub = threadIdx.x & 15;
    const int b_sub = threadIdx.x >> 4;
    const int o  = blockIdx.x * 16 + o_sub;
    const int b0 = blockIdx.y * 16;
    const int i0 = blockIdx.z * ICHUNK;

    // Stage t = exp(x) for this block's 16 b-rows x ICHUNK i's (4 per thread).
    {
        const int brow = threadIdx.x >> 4;
        const int ic4  = (threadIdx.x & 15) * 4;
        const float4 xv = *(const float4*)(x + (b0 + brow) * IN_DIM + i0 + ic4);
        t_lds[brow][ic4 + 0] = __expf(xv.x);
        t_lds[brow][ic4 + 1] = __expf(xv.y);
        t_lds[brow][ic4 + 2] = __expf(xv.z);
        t_lds[brow][ic4 + 3] = __expf(xv.w);
    }
    __syncthreads();

    float accP0 = 0.f, accQ0 = 0.f, accP1 = 0.f, accQ1 = 0.f;
    const float4* __restrict__ c = pk4 + ((size_t)i0 * OUT_DIM + o) * 3;

#pragma unroll 2
    for (int ii = 0; ii < ICHUNK; ii += 2) {
        {
            const float t  = t_lds[b_sub][ii];
            const float t2 = t * t;
            const float t4 = t2 * t2;
            const float4 c0 = c[(size_t)(ii * OUT_DIM) * 3 + 0];
            const float4 c1 = c[(size_t)(ii * OUT_DIM) * 3 + 1];
            const float4 c2 = c[(size_t)(ii * OUT_DIM) * 3 + 2];
            // Estrin: depth-3
            const float P = fmaf(fmaf(c1.y, t, c1.x), t4,
                            fmaf(fmaf(c0.w, t, c0.z), t2, fmaf(c0.y, t, c0.x)));
            const float Q = fmaf(fmaf(c2.w, t, c2.z), t4,
                            fmaf(fmaf(c2.y, t, c2.x), t2, fmaf(c1.w, t, c1.z)));
            accP0 += __log2f(P);
            accQ0 += __log2f(Q);
        }
        {
            const float t  = t_lds[b_sub][ii + 1];
            const float t2 = t * t;
            const float t4 = t2 * t2;
            const float4 c0 = c[(size_t)((ii + 1) * OUT_DIM) * 3 + 0];
            const float4 c1 = c[(size_t)((ii + 1) * OUT_DIM) * 3 + 1];
            const float4 c2 = c[(size_t)((ii + 1) * OUT_DIM) * 3 + 2];
            const float P = fmaf(fmaf(c1.y, t, c1.x), t4,
                            fmaf(fmaf(c0.w, t, c0.z), t2, fmaf(c0.y, t, c0.x)));
            const float Q = fmaf(fmaf(c2.w, t, c2.z), t4,
                            fmaf(fmaf(c2.y, t, c2.x), t2, fmaf(c1.w, t, c1.z)));
            accP1 += __log2f(P);
            accQ1 += __log2f(Q);
        }
    }

    partial[((size_t)blockIdx.z * BATCH + b0 + b_sub) * OUT_DIM + o] =
        (accP0 + accP1) - (accQ0 + accQ1);
}

__global__ void tropical_reduce(const float* __restrict__ partial,
                                float* __restrict__ out) {
    const int j = blockIdx.x * blockDim.x + threadIdx.x;   // 0..B*OUT-1
    const int N = BATCH * OUT_DIM;
    float s = partial[j] + partial[j + N] + partial[j + 2 * N] + partial[j + 3 * N];
    out[j] = s * 0.6931471805599453f;   // * ln2
}

// Fallback (workspace too small): direct stabilized LSE.
__global__ void tropical_fallback(const float* __restrict__ x,
                                  const float* __restrict__ wp,
                                  const float* __restrict__ wq,
                                  float* __restrict__ out) {
    const int o = blockIdx.x * 16 + (threadIdx.x & 15);
    const int b = blockIdx.y * 16 + (threadIdx.x >> 4);
    float acc = 0.f;
    for (int i = 0; i < IN_DIM; ++i) {
        const float xv = x[b * IN_DIM + i];
        const float* p = wp + (size_t)(i * OUT_DIM + o) * NDEG;
        const float* q = wq + (size_t)(i * OUT_DIM + o) * NDEG;
        float lp[NDEG], lq[NDEG], mP = -1e30f, mQ = -1e30f;
#pragma unroll
        for (int d = 0; d < NDEG; ++d) {
            lp[d] = xv * d + p[d]; mP = fmaxf(mP, lp[d]);
            lq[d] = xv * d + q[d]; mQ = fmaxf(mQ, lq[d]);
        }
        float sP = 0.f, sQ = 0.f;
#pragma unroll
        for (int d = 0; d < NDEG; ++d) {
            sP += __expf(lp[d] - mP);
            sQ += __expf(lq[d] - mQ);
        }
        acc += (mP + __logf(sP)) - (mQ + __logf(sQ));
    }
    out[b * OUT_DIM + o] = acc;
}

extern "C" void kernel_launch(void* const* d_in, const int* in_sizes, int n_in,
                              void* d_out, int out_size, void* d_ws, size_t ws_size,
                              hipStream_t stream) {
    const float* x  = (const float*)d_in[0];
    // d_in[1] = slopes (arange(6)) — implicit in the polynomial powers.
    const float* wp = (const float*)d_in[2];
    const float* wq = (const float*)d_in[3];
    float* out = (float*)d_out;

    const size_t pk_bytes      = (size_t)IN_DIM * OUT_DIM * 12 * sizeof(float);   // 3 MiB
    const size_t partial_bytes = (size_t)NCHUNK * BATCH * OUT_DIM * sizeof(float); // 2 MiB

    if (ws_size >= pk_bytes + partial_bytes) {
        float4* pk      = (float4*)d_ws;
        float*  partial = (float*)((char*)d_ws + pk_bytes);

        prep_pack<<<(IN_DIM * OUT_DIM + 255) / 256, 256, 0, stream>>>(wp, wq, pk);

        dim3 grid(OUT_DIM / 16, BATCH / 16, NCHUNK);
        tropical_main<<<grid, 256, 0, stream>>>(x, (const float4*)pk, partial);

        tropical_reduce<<<(BATCH * OUT_DIM) / 256, 256, 0, stream>>>(partial, out);
    } else {
        dim3 grid(OUT_DIM / 16, BATCH / 16);
        tropical_fallback<<<grid, 256, 0, stream>>>(x, wp, wq, out);
    }
}

// Round 3
// 28.329 us; speedup vs baseline: 2.0816x; 1.9936x over previous
//
#include <hip/hip_runtime.h>
#include <math.h>

#define BATCH   512
#define IN_DIM  256
#define OUT_DIM 256
#define NDEG    6     // degree+1

// Block geometry for tropical_main:
//   256 threads = 8 o-lanes (minor) x 32 i-segments; each thread keeps 16
//   b-accumulators in registers -> each 48B coefficient bundle is loaded ONCE
//   and reused 16x (vs 1x in R2, which was VMEM-instruction-bound).
#define OT    8     // o per block
#define NSEG  32    // i-segments per block
#define ISEG  8     // i's per segment (NSEG*ISEG == IN_DIM)
#define NB    16    // b per block (register accumulators per thread)

// ---------------------------------------------------------------------------
// LSE_d(x*d + w_d) = log( sum_d e^{w_d} * t^d ),  t = e^x.
// out[b,o] = ln2 * sum_i [ log2 P_io(t_bi) - log2 Q_io(t_bi) ]
// Coefficients exp(w) precomputed in transposed layout pkT[(i*3+w)*256+o]
// (float4 per (i,o,w)) so coefficient loads are lane-contiguous.
// ---------------------------------------------------------------------------

__global__ void prep_pack(const float* __restrict__ wp,
                          const float* __restrict__ wq,
                          float4* __restrict__ pkT) {
    int j = blockIdx.x * blockDim.x + threadIdx.x;   // j = i*OUT_DIM + o
    if (j >= IN_DIM * OUT_DIM) return;
    const int i = j >> 8, o = j & 255;
    const float2* wp2 = (const float2*)wp;
    const float2* wq2 = (const float2*)wq;
    float2 p0 = wp2[j * 3], p1 = wp2[j * 3 + 1], p2 = wp2[j * 3 + 2];
    float2 q0 = wq2[j * 3], q1 = wq2[j * 3 + 1], q2 = wq2[j * 3 + 2];
    pkT[(i * 3 + 0) * OUT_DIM + o] =
        make_float4(__expf(p0.x), __expf(p0.y), __expf(p1.x), __expf(p1.y));
    pkT[(i * 3 + 1) * OUT_DIM + o] =
        make_float4(__expf(p2.x), __expf(p2.y), __expf(q0.x), __expf(q0.y));
    pkT[(i * 3 + 2) * OUT_DIM + o] =
        make_float4(__expf(q1.x), __expf(q1.y), __expf(q2.x), __expf(q2.y));
}

// Grid = (OUT_DIM/OT = 32, BATCH/NB = 32). 1024 blocks = 4/CU.
__launch_bounds__(256, 4)
__global__ void tropical_main(const float* __restrict__ x,
                              const float4* __restrict__ pkT,
                              float* __restrict__ out) {
    // Phase A: t[b][i] for 16 b x 256 i (16 KiB).  Phase B (after sync):
    // reduce buffer red[seg][b*8+o], slab stride 129 (pad: seg slabs shift
    // banks by 1).  Same allocation, max(4096, 32*129=4128) words.
    __shared__ float lds[NSEG * (NB * OT + 1)];   // 4128 floats

    const int tid = threadIdx.x;
    const int o_l = tid & (OT - 1);        // 0..7, lane-minor -> coalesced
    const int seg = tid >> 3;              // 0..31
    const int o   = blockIdx.x * OT + o_l;
    const int b0  = blockIdx.y * NB;

    // ---- stage t = exp(x) for this block's 16 b-rows x all 256 i ----
    {
        const int br  = tid >> 4;          // 0..15
        const int s16 = tid & 15;          // 0..15
        const float4* xr = (const float4*)(x + (size_t)(b0 + br) * IN_DIM) + s16 * 4;
#pragma unroll
        for (int k = 0; k < 4; ++k) {
            const float4 v = xr[k];
            const int base = br * IN_DIM + s16 * 16 + k * 4;
            lds[base + 0] = __expf(v.x);
            lds[base + 1] = __expf(v.y);
            lds[base + 2] = __expf(v.z);
            lds[base + 3] = __expf(v.w);
        }
    }
    __syncthreads();

    float acc[NB];
#pragma unroll
    for (int b = 0; b < NB; ++b) acc[b] = 0.f;

    const int i0 = seg * ISEG;
    const float4* __restrict__ cbase = pkT + (size_t)(i0 * 3) * OUT_DIM + o;

#pragma unroll 2
    for (int ii = 0; ii < ISEG; ++ii) {
        const float4 c0 = cbase[(ii * 3 + 0) * OUT_DIM];
        const float4 c1 = cbase[(ii * 3 + 1) * OUT_DIM];
        const float4 c2 = cbase[(ii * 3 + 2) * OUT_DIM];
        const float* __restrict__ tcol = lds + (i0 + ii);   // t[b][i] @ b*256+i
#pragma unroll
        for (int b = 0; b < NB; ++b) {
            const float t  = tcol[b * IN_DIM];   // wave-broadcast LDS read
            const float t2 = t * t;
            const float t4 = t2 * t2;
            // Estrin depth-3: P = c0.x + c0.y t + c0.z t2 + c0.w t3 + c1.x t4 + c1.y t5
            const float P = fmaf(fmaf(c1.y, t, c1.x), t4,
                            fmaf(fmaf(c0.w, t, c0.z), t2, fmaf(c0.y, t, c0.x)));
            const float Q = fmaf(fmaf(c2.w, t, c2.z), t4,
                            fmaf(fmaf(c2.y, t, c2.x), t2, fmaf(c1.w, t, c1.z)));
            acc[b] += __log2f(P) - __log2f(Q);
        }
    }

    __syncthreads();   // done with t; reuse LDS as reduce buffer
#pragma unroll
    for (int b = 0; b < NB; ++b)
        lds[seg * (NB * OT + 1) + b * OT + o_l] = acc[b];
    __syncthreads();

    if (tid < NB * OT) {
        const int br = tid >> 3, orr = tid & (OT - 1);
        float s = 0.f;
#pragma unroll
        for (int g = 0; g < NSEG; ++g)
            s += lds[g * (NB * OT + 1) + br * OT + orr];
        out[(size_t)(b0 + br) * OUT_DIM + blockIdx.x * OT + orr] =
            s * 0.6931471805599453f;   // * ln2
    }
}

// Fallback (workspace too small): direct stabilized LSE.
__global__ void tropical_fallback(const float* __restrict__ x,
                                  const float* __restrict__ wp,
                                  const float* __restrict__ wq,
                                  float* __restrict__ out) {
    const int o = blockIdx.x * 16 + (threadIdx.x & 15);
    const int b = blockIdx.y * 16 + (threadIdx.x >> 4);
    float acc = 0.f;
    for (int i = 0; i < IN_DIM; ++i) {
        const float xv = x[b * IN_DIM + i];
        const float* p = wp + (size_t)(i * OUT_DIM + o) * NDEG;
        const float* q = wq + (size_t)(i * OUT_DIM + o) * NDEG;
        float lp[NDEG], lq[NDEG], mP = -1e30f, mQ = -1e30f;
#pragma unroll
        for (int d = 0; d < NDEG; ++d) {
            lp[d] = xv * d + p[d]; mP = fmaxf(mP, lp[d]);
            lq[d] = xv * d + q[d]; mQ = fmaxf(mQ, lq[d]);
        }
        float sP = 0.f, sQ = 0.f;
#pragma unroll
        for (int d = 0; d < NDEG; ++d) {
            sP += __expf(lp[d] - mP);
            sQ += __expf(lq[d] - mQ);
        }
        acc += (mP + __logf(sP)) - (mQ + __logf(sQ));
    }
    out[b * OUT_DIM + o] = acc;
}

extern "C" void kernel_launch(void* const* d_in, const int* in_sizes, int n_in,
                              void* d_out, int out_size, void* d_ws, size_t ws_size,
                              hipStream_t stream) {
    const float* x  = (const float*)d_in[0];
    // d_in[1] = slopes (arange(6)) — implicit in the polynomial powers.
    const float* wp = (const float*)d_in[2];
    const float* wq = (const float*)d_in[3];
    float* out = (float*)d_out;

    const size_t pk_bytes = (size_t)IN_DIM * OUT_DIM * 12 * sizeof(float);  // 3 MiB

    if (ws_size >= pk_bytes) {
        float4* pkT = (float4*)d_ws;
        prep_pack<<<(IN_DIM * OUT_DIM + 255) / 256, 256, 0, stream>>>(wp, wq, pkT);

        dim3 grid(OUT_DIM / OT, BATCH / NB);   // 32 x 32 = 1024 blocks
        tropical_main<<<grid, 256, 0, stream>>>(x, (const float4*)pkT, out);
    } else {
        dim3 grid(OUT_DIM / 16, BATCH / 16);
        tropical_fallback<<<grid, 256, 0, stream>>>(x, wp, wq, out);
    }
}